// Round 1
// baseline (692.600 us; speedup 1.0000x reference)
//
#include <hip/hip_runtime.h>

constexpr int N_NODES = 100000;
constexpr int N_EDGES = 1600000;
constexpr int D = 32;

// Kernel 1: msg = relu(x[src] + e); atomic scatter-add into agg (= d_out).
// One float4 per thread -> 8 threads per edge, coalesced edge reads.
__global__ __launch_bounds__(256) void gine_edge_kernel(
    const float* __restrict__ node, const float* __restrict__ edge,
    const int* __restrict__ src, const int* __restrict__ dst,
    float* __restrict__ agg)
{
    const long long total = (long long)N_EDGES * (D / 4);   // 12.8M float4 items
    long long idx = (long long)blockIdx.x * blockDim.x + threadIdx.x;
    const long long stride = (long long)gridDim.x * blockDim.x;
    for (; idx < total; idx += stride) {
        const int e = (int)(idx >> 3);
        const int q = (int)(idx & 7);
        const int s  = src[e];
        const int dv = dst[e];
        const float4 ev = reinterpret_cast<const float4*>(edge)[idx];
        const float4 nv = reinterpret_cast<const float4*>(node)[(long long)s * (D / 4) + q];
        float4 m;
        m.x = fmaxf(ev.x + nv.x, 0.0f);
        m.y = fmaxf(ev.y + nv.y, 0.0f);
        m.z = fmaxf(ev.z + nv.z, 0.0f);
        m.w = fmaxf(ev.w + nv.w, 0.0f);
        float* p = agg + (long long)dv * D + q * 4;
        atomicAdd(p + 0, m.x);
        atomicAdd(p + 1, m.y);
        atomicAdd(p + 2, m.z);
        atomicAdd(p + 3, m.w);
    }
}

// Kernel 2: h = (1+eps)*x + agg; out = h @ W^T + b. In-place on d_out.
// One 32-lane group per node row; W staged in padded LDS; row broadcast via shfl.
__global__ __launch_bounds__(256) void gine_node_kernel(
    const float* __restrict__ node, const float* __restrict__ W,
    const float* __restrict__ b, const float* __restrict__ eps,
    float* __restrict__ inout)
{
    __shared__ float Ws[D][D + 1];   // +1 pad: lane o reads Ws[o][k] conflict-free
    __shared__ float bs[D];
    const int t = threadIdx.x;
    for (int i = t; i < D * D; i += blockDim.x) Ws[i >> 5][i & 31] = W[i];
    if (t < D) bs[t] = b[t];
    __syncthreads();

    const float scale = 1.0f + eps[0];
    const long long gid = (long long)blockIdx.x * blockDim.x + t;
    if (gid >= (long long)N_NODES * D) return;
    const int o = (int)(gid & 31);          // output feature
    const float h = scale * node[gid] + inout[gid];   // h[i, o] in this lane

    float acc = bs[o];
    #pragma unroll
    for (int k = 0; k < D; ++k) {
        const float hk = __shfl(h, k, 32);  // broadcast h[i,k] within the 32-group
        acc += hk * Ws[o][k];
    }
    inout[gid] = acc;   // all shfl reads of h (registers) complete before this store
}

extern "C" void kernel_launch(void* const* d_in, const int* in_sizes, int n_in,
                              void* d_out, int out_size, void* d_ws, size_t ws_size,
                              hipStream_t stream) {
    const float* node = (const float*)d_in[0];
    const float* edge = (const float*)d_in[1];
    const int*   src  = (const int*)d_in[2];
    const int*   dst  = (const int*)d_in[3];
    const float* W    = (const float*)d_in[4];
    const float* b    = (const float*)d_in[5];
    const float* eps  = (const float*)d_in[6];
    float* out = (float*)d_out;

    // Zero the accumulator (d_out doubles as agg buffer).
    hipMemsetAsync(out, 0, (size_t)N_NODES * D * sizeof(float), stream);

    // Edge scatter: grid-stride over 12.8M float4 items.
    gine_edge_kernel<<<4096, 256, 0, stream>>>(node, edge, src, dst, out);

    // Node update + linear, in place.
    const int total_threads = N_NODES * D;
    const int blocks = (total_threads + 255) / 256;
    gine_node_kernel<<<blocks, 256, 0, stream>>>(node, W, b, eps, out);
}

// Round 2
// 574.502 us; speedup vs baseline: 1.2056x; 1.2056x over previous
//
#include <hip/hip_runtime.h>

constexpr int N_NODES = 100000;
constexpr int N_EDGES = 1600000;
constexpr int D = 32;
constexpr int SCAN_T = 1024;

// K1: histogram of destination degrees (int atomics into L2-resident 400KB).
__global__ __launch_bounds__(256) void hist_kernel(const int* __restrict__ dst,
                                                   int* __restrict__ cnt) {
    int e = blockIdx.x * blockDim.x + threadIdx.x;
    if (e < N_EDGES) atomicAdd(&cnt[dst[e]], 1);
}

// K2: exclusive scan of cnt -> off, and a second copy -> cur (scatter cursors).
// Single block of 1024 threads; each owns a contiguous chunk.
__global__ __launch_bounds__(SCAN_T) void scan_kernel(const int* __restrict__ cnt,
                                                      int* __restrict__ off,
                                                      int* __restrict__ cur) {
    __shared__ int part[SCAN_T];
    const int CHUNK = (N_NODES + SCAN_T - 1) / SCAN_T;   // 98
    const int t = threadIdx.x;
    const int base = t * CHUNK;
    int sum = 0;
    for (int j = 0; j < CHUNK; ++j) {
        int i = base + j;
        if (i < N_NODES) sum += cnt[i];
    }
    part[t] = sum;
    __syncthreads();
    // Hillis-Steele inclusive scan over the 1024 partials.
    for (int d = 1; d < SCAN_T; d <<= 1) {
        int v = (t >= d) ? part[t - d] : 0;
        __syncthreads();
        part[t] += v;
        __syncthreads();
    }
    int run = (t == 0) ? 0 : part[t - 1];
    for (int j = 0; j < CHUNK; ++j) {
        int i = base + j;
        if (i < N_NODES) {
            off[i] = run;
            cur[i] = run;
            run += cnt[i];
        }
    }
}

// K3: scatter edge ids into CSR order.
__global__ __launch_bounds__(256) void scatter_kernel(const int* __restrict__ dst,
                                                      int* __restrict__ cur,
                                                      int* __restrict__ eid) {
    int e = blockIdx.x * blockDim.x + threadIdx.x;
    if (e >= N_EDGES) return;
    int pos = atomicAdd(&cur[dst[e]], 1);
    eid[pos] = e;
}

// K4: per-node gather-sum + eps-update + 32x32 linear, fused.
// 32 lanes per node (lane o = feature o), 8 nodes per 256-thread block.
__global__ __launch_bounds__(256) void gather_node_kernel(
    const float* __restrict__ node, const float* __restrict__ edge,
    const int* __restrict__ src, const int* __restrict__ off,
    const int* __restrict__ cnt, const int* __restrict__ eid,
    const float* __restrict__ W, const float* __restrict__ b,
    const float* __restrict__ eps, float* __restrict__ out)
{
    __shared__ float Ws[D][D + 1];   // +1 pad: Ws[o][k] conflict-free per lane o
    __shared__ float bs[D];
    const int t = threadIdx.x;
    for (int i = t; i < D * D; i += blockDim.x) Ws[i >> 5][i & 31] = W[i];
    if (t < D) bs[t] = b[t];
    __syncthreads();

    const int g = t >> 5;                       // node group within block
    const int o = t & 31;                       // feature index
    const int nodeid = blockIdx.x * 8 + g;
    if (nodeid >= N_NODES) return;

    const int start = off[nodeid];
    const int n = cnt[nodeid];
    float acc = 0.0f;
    int j = 0;
    // 2-edge unroll for load-latency overlap.
    for (; j + 1 < n; j += 2) {
        const int e0 = eid[start + j];
        const int e1 = eid[start + j + 1];
        const int s0 = src[e0];
        const int s1 = src[e1];
        const float ev0 = edge[(long long)e0 * D + o];
        const float nv0 = node[(long long)s0 * D + o];
        const float ev1 = edge[(long long)e1 * D + o];
        const float nv1 = node[(long long)s1 * D + o];
        acc += fmaxf(ev0 + nv0, 0.0f);
        acc += fmaxf(ev1 + nv1, 0.0f);
    }
    if (j < n) {
        const int e0 = eid[start + j];
        const int s0 = src[e0];
        acc += fmaxf(edge[(long long)e0 * D + o] + node[(long long)s0 * D + o], 0.0f);
    }

    const float scale = 1.0f + eps[0];
    const float h = scale * node[(long long)nodeid * D + o] + acc;

    float r = bs[o];
    #pragma unroll
    for (int k = 0; k < D; ++k) r += __shfl(h, k, 32) * Ws[o][k];
    out[(long long)nodeid * D + o] = r;
}

extern "C" void kernel_launch(void* const* d_in, const int* in_sizes, int n_in,
                              void* d_out, int out_size, void* d_ws, size_t ws_size,
                              hipStream_t stream) {
    const float* node = (const float*)d_in[0];
    const float* edge = (const float*)d_in[1];
    const int*   src  = (const int*)d_in[2];
    const int*   dst  = (const int*)d_in[3];
    const float* W    = (const float*)d_in[4];
    const float* b    = (const float*)d_in[5];
    const float* eps  = (const float*)d_in[6];
    float* out = (float*)d_out;

    // Workspace layout: cnt[N] | off[N] | cur[N] | eid[E]   (7.6 MB total)
    int* cnt = (int*)d_ws;
    int* off = cnt + N_NODES;
    int* cur = off + N_NODES;
    int* eid = cur + N_NODES;

    hipMemsetAsync(cnt, 0, (size_t)N_NODES * sizeof(int), stream);

    const int eb = (N_EDGES + 255) / 256;
    hist_kernel<<<eb, 256, 0, stream>>>(dst, cnt);
    scan_kernel<<<1, SCAN_T, 0, stream>>>(cnt, off, cur);
    scatter_kernel<<<eb, 256, 0, stream>>>(dst, cur, eid);

    const int nb = (N_NODES + 7) / 8;
    gather_node_kernel<<<nb, 256, 0, stream>>>(node, edge, src, off, cnt, eid,
                                               W, b, eps, out);
}

// Round 3
// 322.087 us; speedup vs baseline: 2.1504x; 1.7837x over previous
//
#include <hip/hip_runtime.h>

constexpr int N_NODES = 100000;
constexpr int N_EDGES = 1600000;
constexpr int D = 32;
constexpr int SCAN_B = 256;
constexpr int NB = (N_NODES + SCAN_B - 1) / SCAN_B;   // 391 scan blocks

// K1: histogram of destination degrees (int atomics, L2-resident 400KB).
__global__ __launch_bounds__(256) void hist_kernel(const int* __restrict__ dst,
                                                   int* __restrict__ cnt) {
    int e = blockIdx.x * blockDim.x + threadIdx.x;
    if (e < N_EDGES) atomicAdd(&cnt[dst[e]], 1);
}

__device__ inline int wave_incl_scan(int v, int lane) {
    #pragma unroll
    for (int d = 1; d < 64; d <<= 1) {
        int u = __shfl_up(v, d, 64);
        if (lane >= d) v += u;
    }
    return v;
}

// K2a: per-block sums of cnt.
__global__ __launch_bounds__(SCAN_B) void scan_a(const int* __restrict__ cnt,
                                                 int* __restrict__ bsum) {
    __shared__ int ws[SCAN_B / 64];
    int i = blockIdx.x * SCAN_B + threadIdx.x;
    int v = (i < N_NODES) ? cnt[i] : 0;
    #pragma unroll
    for (int d = 32; d >= 1; d >>= 1) v += __shfl_down(v, d, 64);
    if ((threadIdx.x & 63) == 0) ws[threadIdx.x >> 6] = v;
    __syncthreads();
    if (threadIdx.x == 0) bsum[blockIdx.x] = ws[0] + ws[1] + ws[2] + ws[3];
}

// K2b: exclusive scan of the NB block sums (single block).
__global__ __launch_bounds__(512) void scan_b(const int* __restrict__ bsum,
                                              int* __restrict__ boff) {
    __shared__ int part[512];
    const int t = threadIdx.x;
    int v = (t < NB) ? bsum[t] : 0;
    part[t] = v;
    __syncthreads();
    for (int d = 1; d < 512; d <<= 1) {
        int u = (t >= d) ? part[t - d] : 0;
        __syncthreads();
        part[t] += u;
        __syncthreads();
    }
    if (t < NB) boff[t] = part[t] - v;   // exclusive
}

// K2c: local exclusive scan + block offset -> off, cur.
__global__ __launch_bounds__(SCAN_B) void scan_c(const int* __restrict__ cnt,
                                                 const int* __restrict__ boff,
                                                 int* __restrict__ off,
                                                 int* __restrict__ cur) {
    __shared__ int wsum[SCAN_B / 64];
    const int i = blockIdx.x * SCAN_B + threadIdx.x;
    const int lane = threadIdx.x & 63;
    const int w = threadIdx.x >> 6;
    int v = (i < N_NODES) ? cnt[i] : 0;
    int incl = wave_incl_scan(v, lane);
    if (lane == 63) wsum[w] = incl;
    __syncthreads();
    int wo = 0;
    for (int k = 0; k < w; ++k) wo += wsum[k];
    const int excl = incl - v + wo + boff[blockIdx.x];
    if (i < N_NODES) { off[i] = excl; cur[i] = excl; }
}

// K3: scatter edge ids into CSR order.
__global__ __launch_bounds__(256) void scatter_kernel(const int* __restrict__ dst,
                                                      int* __restrict__ cur,
                                                      int* __restrict__ eid) {
    int e = blockIdx.x * blockDim.x + threadIdx.x;
    if (e >= N_EDGES) return;
    int pos = atomicAdd(&cur[dst[e]], 1);
    eid[pos] = e;
}

// K4: per-node gather-sum + eps-update + 32x32 linear, fused.
__global__ __launch_bounds__(256) void gather_node_kernel(
    const float* __restrict__ node, const float* __restrict__ edge,
    const int* __restrict__ src, const int* __restrict__ off,
    const int* __restrict__ cnt, const int* __restrict__ eid,
    const float* __restrict__ W, const float* __restrict__ b,
    const float* __restrict__ eps, float* __restrict__ out)
{
    __shared__ float Ws[D][D + 1];
    __shared__ float bs[D];
    const int t = threadIdx.x;
    for (int i = t; i < D * D; i += blockDim.x) Ws[i >> 5][i & 31] = W[i];
    if (t < D) bs[t] = b[t];
    __syncthreads();

    const int g = t >> 5;
    const int o = t & 31;
    const int nodeid = blockIdx.x * 8 + g;
    if (nodeid >= N_NODES) return;

    const int start = off[nodeid];
    const int n = cnt[nodeid];
    float acc = 0.0f;
    int j = 0;
    for (; j + 1 < n; j += 2) {
        const int e0 = eid[start + j];
        const int e1 = eid[start + j + 1];
        const int s0 = src[e0];
        const int s1 = src[e1];
        const float ev0 = edge[(long long)e0 * D + o];
        const float nv0 = node[(long long)s0 * D + o];
        const float ev1 = edge[(long long)e1 * D + o];
        const float nv1 = node[(long long)s1 * D + o];
        acc += fmaxf(ev0 + nv0, 0.0f);
        acc += fmaxf(ev1 + nv1, 0.0f);
    }
    if (j < n) {
        const int e0 = eid[start + j];
        const int s0 = src[e0];
        acc += fmaxf(edge[(long long)e0 * D + o] + node[(long long)s0 * D + o], 0.0f);
    }

    const float scale = 1.0f + eps[0];
    const float h = scale * node[(long long)nodeid * D + o] + acc;

    float r = bs[o];
    #pragma unroll
    for (int k = 0; k < D; ++k) r += __shfl(h, k, 32) * Ws[o][k];
    out[(long long)nodeid * D + o] = r;
}

extern "C" void kernel_launch(void* const* d_in, const int* in_sizes, int n_in,
                              void* d_out, int out_size, void* d_ws, size_t ws_size,
                              hipStream_t stream) {
    const float* node = (const float*)d_in[0];
    const float* edge = (const float*)d_in[1];
    const int*   src  = (const int*)d_in[2];
    const int*   dst  = (const int*)d_in[3];
    const float* W    = (const float*)d_in[4];
    const float* b    = (const float*)d_in[5];
    const float* eps  = (const float*)d_in[6];
    float* out = (float*)d_out;

    // Workspace: cnt[N] | off[N] | cur[N] | eid[E] | bsum[NB] | boff[NB]
    int* cnt  = (int*)d_ws;
    int* off  = cnt + N_NODES;
    int* cur  = off + N_NODES;
    int* eid  = cur + N_NODES;
    int* bsum = eid + N_EDGES;
    int* boff = bsum + NB;

    hipMemsetAsync(cnt, 0, (size_t)N_NODES * sizeof(int), stream);

    const int eb = (N_EDGES + 255) / 256;
    hist_kernel<<<eb, 256, 0, stream>>>(dst, cnt);
    scan_a<<<NB, SCAN_B, 0, stream>>>(cnt, bsum);
    scan_b<<<1, 512, 0, stream>>>(bsum, boff);
    scan_c<<<NB, SCAN_B, 0, stream>>>(cnt, boff, off, cur);
    scatter_kernel<<<eb, 256, 0, stream>>>(dst, cur, eid);

    const int nb = (N_NODES + 7) / 8;
    gather_node_kernel<<<nb, 256, 0, stream>>>(node, edge, src, off, cnt, eid,
                                               W, b, eps, out);
}

// Round 4
// 285.402 us; speedup vs baseline: 2.4268x; 1.1285x over previous
//
#include <hip/hip_runtime.h>

constexpr int N_NODES = 100000;
constexpr int N_EDGES = 1600000;
constexpr int D = 32;
constexpr int SCAN_B = 256;
constexpr int NB = (N_NODES + SCAN_B - 1) / SCAN_B;   // 391 scan blocks

// K1: histogram of destination degrees (int atomics, L2-resident 400KB).
// int4-vectorized dst reads.
__global__ __launch_bounds__(256) void hist_kernel(const int4* __restrict__ dst4,
                                                   int* __restrict__ cnt) {
    int i = blockIdx.x * blockDim.x + threadIdx.x;
    if (i < N_EDGES / 4) {
        int4 d = dst4[i];
        atomicAdd(&cnt[d.x], 1);
        atomicAdd(&cnt[d.y], 1);
        atomicAdd(&cnt[d.z], 1);
        atomicAdd(&cnt[d.w], 1);
    }
}

__device__ inline int wave_incl_scan(int v, int lane) {
    #pragma unroll
    for (int d = 1; d < 64; d <<= 1) {
        int u = __shfl_up(v, d, 64);
        if (lane >= d) v += u;
    }
    return v;
}

// K2a: per-block sums of cnt.
__global__ __launch_bounds__(SCAN_B) void scan_a(const int* __restrict__ cnt,
                                                 int* __restrict__ bsum) {
    __shared__ int ws[SCAN_B / 64];
    int i = blockIdx.x * SCAN_B + threadIdx.x;
    int v = (i < N_NODES) ? cnt[i] : 0;
    #pragma unroll
    for (int d = 32; d >= 1; d >>= 1) v += __shfl_down(v, d, 64);
    if ((threadIdx.x & 63) == 0) ws[threadIdx.x >> 6] = v;
    __syncthreads();
    if (threadIdx.x == 0) bsum[blockIdx.x] = ws[0] + ws[1] + ws[2] + ws[3];
}

// K2b: exclusive scan of the NB block sums (single block).
__global__ __launch_bounds__(512) void scan_b(const int* __restrict__ bsum,
                                              int* __restrict__ boff) {
    __shared__ int part[512];
    const int t = threadIdx.x;
    int v = (t < NB) ? bsum[t] : 0;
    part[t] = v;
    __syncthreads();
    for (int d = 1; d < 512; d <<= 1) {
        int u = (t >= d) ? part[t - d] : 0;
        __syncthreads();
        part[t] += u;
        __syncthreads();
    }
    if (t < NB) boff[t] = part[t] - v;   // exclusive
}

// K2c: local exclusive scan + block offset -> offcnt (packed), cur.
__global__ __launch_bounds__(SCAN_B) void scan_c(const int* __restrict__ cnt,
                                                 const int* __restrict__ boff,
                                                 int2* __restrict__ offcnt,
                                                 int* __restrict__ cur) {
    __shared__ int wsum[SCAN_B / 64];
    const int i = blockIdx.x * SCAN_B + threadIdx.x;
    const int lane = threadIdx.x & 63;
    const int w = threadIdx.x >> 6;
    int v = (i < N_NODES) ? cnt[i] : 0;
    int incl = wave_incl_scan(v, lane);
    if (lane == 63) wsum[w] = incl;
    __syncthreads();
    int wo = 0;
    for (int k = 0; k < w; ++k) wo += wsum[k];
    const int excl = incl - v + wo + boff[blockIdx.x];
    if (i < N_NODES) {
        offcnt[i] = make_int2(excl, v);
        cur[i] = excl;
    }
}

// K3: scatter edge ids into CSR order (int4 dst reads).
__global__ __launch_bounds__(256) void scatter_kernel(const int4* __restrict__ dst4,
                                                      int* __restrict__ cur,
                                                      int* __restrict__ eid) {
    int i = blockIdx.x * blockDim.x + threadIdx.x;
    if (i >= N_EDGES / 4) return;
    int4 d = dst4[i];
    const int e = i * 4;
    eid[atomicAdd(&cur[d.x], 1)] = e;
    eid[atomicAdd(&cur[d.y], 1)] = e + 1;
    eid[atomicAdd(&cur[d.z], 1)] = e + 2;
    eid[atomicAdd(&cur[d.w], 1)] = e + 3;
}

// K4: per-node gather-sum + eps-update + 32x32 linear, fused.
// 32 lanes per node. Cooperative index prefetch (one coalesced eid load +
// one src gather per 32 edges), then 8-wide batches of independent row loads.
__global__ __launch_bounds__(256) void gather_node_kernel(
    const float* __restrict__ node, const float* __restrict__ edge,
    const int* __restrict__ src, const int2* __restrict__ offcnt,
    const int* __restrict__ eid,
    const float* __restrict__ W, const float* __restrict__ b,
    const float* __restrict__ eps, float* __restrict__ out)
{
    __shared__ float Ws[D][D + 1];
    __shared__ float bs[D];
    const int t = threadIdx.x;
    for (int i = t; i < D * D; i += blockDim.x) Ws[i >> 5][i & 31] = W[i];
    if (t < D) bs[t] = b[t];
    __syncthreads();

    const int g = t >> 5;
    const int o = t & 31;
    const int nodeid = blockIdx.x * 8 + g;
    if (nodeid >= N_NODES) return;

    const int2 oc = offcnt[nodeid];
    const int start = oc.x;
    const int n = oc.y;
    float acc = 0.0f;

    for (int c = 0; c < n; c += 32) {
        const int m = min(32, n - c);          // >= 1
        // Cooperative prefetch: lane o holds edge (c+o)'s id and src.
        int e_l = 0, s_l = 0;
        if (o < m) {
            e_l = eid[start + c + o];          // coalesced
            s_l = src[e_l];                    // 4B gather
        }
        // 8-wide predicated batches: 16 independent loads in flight.
        for (int j = 0; j < m; j += 8) {
            float ev[8], nv[8];
            #pragma unroll
            for (int u = 0; u < 8; ++u) {
                const int jj = j + u;
                const int lsrc = (jj < m) ? jj : (m - 1);   // clamp: valid dup row
                const int e = __shfl(e_l, lsrc, 32);
                const int s = __shfl(s_l, lsrc, 32);
                ev[u] = edge[(long long)e * D + o];
                nv[u] = node[(long long)s * D + o];
            }
            #pragma unroll
            for (int u = 0; u < 8; ++u) {
                if (j + u < m) acc += fmaxf(ev[u] + nv[u], 0.0f);
            }
        }
    }

    const float scale = 1.0f + eps[0];
    const float h = scale * node[(long long)nodeid * D + o] + acc;

    float r = bs[o];
    #pragma unroll
    for (int k = 0; k < D; ++k) r += __shfl(h, k, 32) * Ws[o][k];
    out[(long long)nodeid * D + o] = r;
}

extern "C" void kernel_launch(void* const* d_in, const int* in_sizes, int n_in,
                              void* d_out, int out_size, void* d_ws, size_t ws_size,
                              hipStream_t stream) {
    const float* node = (const float*)d_in[0];
    const float* edge = (const float*)d_in[1];
    const int*   src  = (const int*)d_in[2];
    const int*   dst  = (const int*)d_in[3];
    const float* W    = (const float*)d_in[4];
    const float* b    = (const float*)d_in[5];
    const float* eps  = (const float*)d_in[6];
    float* out = (float*)d_out;

    // Workspace: offcnt(int2)[N] | cnt[N] | cur[N] | eid[E] | bsum[NB] | boff[NB]
    int2* offcnt = (int2*)d_ws;
    int*  cnt    = (int*)(offcnt + N_NODES);
    int*  cur    = cnt + N_NODES;
    int*  eid    = cur + N_NODES;
    int*  bsum   = eid + N_EDGES;
    int*  boff   = bsum + NB;

    hipMemsetAsync(cnt, 0, (size_t)N_NODES * sizeof(int), stream);

    const int eb4 = (N_EDGES / 4 + 255) / 256;
    hist_kernel<<<eb4, 256, 0, stream>>>((const int4*)dst, cnt);
    scan_a<<<NB, SCAN_B, 0, stream>>>(cnt, bsum);
    scan_b<<<1, 512, 0, stream>>>(bsum, boff);
    scan_c<<<NB, SCAN_B, 0, stream>>>(cnt, boff, offcnt, cur);
    scatter_kernel<<<eb4, 256, 0, stream>>>((const int4*)dst, cur, eid);

    const int nb = (N_NODES + 7) / 8;
    gather_node_kernel<<<nb, 256, 0, stream>>>(node, edge, src, offcnt, eid,
                                               W, b, eps, out);
}